// Round 9
// baseline (455.662 us; speedup 1.0000x reference)
//
#include <hip/hip_runtime.h>
#include <hip/hip_bf16.h>

typedef __bf16 bf16x8 __attribute__((ext_vector_type(8)));
typedef __bf16 bf16x4 __attribute__((ext_vector_type(4)));
typedef float  f32x4  __attribute__((ext_vector_type(4)));

#define BT    2048
#define MDIM  48

// ws byte offsets
#define WS_WVID  0                       // K-major granule layout, 512 KB
#define WS_WV    (512*512*2)
#define WS_WG    (WS_WV + 48*512*2)
#define WS_INTER (WS_WG + 48*512*2)

// ---------------------------------------------------------------- kernel 0
__global__ __launch_bounds__(256) void convert_weights(
    const float* __restrict__ Wvid, const float* __restrict__ Wv,
    const float* __restrict__ Wg,
    __bf16* __restrict__ wvid_k, __bf16* __restrict__ wv_b,
    __bf16* __restrict__ wg_b) {
    int i = blockIdx.x * blockDim.x + threadIdx.x;
    const int nv = 65536, n2 = 6144;
    if (i < nv) {
        int h = i >> 7, k4 = i & 127;    // 128 float4 per 512-elem row
        float4 f = ((const float4*)Wvid)[i];
        bf16x4 o = {(__bf16)f.x, (__bf16)f.y, (__bf16)f.z, (__bf16)f.w};
        *(bf16x4*)(wvid_k + (size_t)(((k4 >> 1) * 512 + h) * 8 + (k4 & 1) * 4)) = o;
    } else if (i < nv + n2) {
        int j = i - nv;
        float4 f = ((const float4*)Wv)[j];
        bf16x4 o = {(__bf16)f.x, (__bf16)f.y, (__bf16)f.z, (__bf16)f.w};
        ((bf16x4*)wv_b)[j] = o;
    } else {
        int j = i - nv - n2;
        float4 f = ((const float4*)Wg)[j];
        bf16x4 o = {(__bf16)f.x, (__bf16)f.y, (__bf16)f.z, (__bf16)f.w};
        ((bf16x4*)wg_b)[j] = o;
    }
}

// ---------------------------------------------------------------- kernel 1
__global__ __launch_bounds__(512) void audio_batch(
    const float* __restrict__ audio, const float* __restrict__ Wa,
    const float* __restrict__ ba, const __bf16* __restrict__ wg_b,
    float* __restrict__ inter) {
    __shared__ float  ain[16 * 128];
    __shared__ __bf16 as_s[64 * 17 * 8];

    const int bt0 = blockIdx.x * 16;
    const int t   = threadIdx.x;

    ((float4*)ain)[t] = ((const float4*)(audio + (size_t)bt0 * 128))[t];
    __syncthreads();

    float acc[16];
    float bias = ba[t];
    #pragma unroll
    for (int b = 0; b < 16; ++b) acc[b] = bias;
    const float4* wr = (const float4*)(Wa + (size_t)t * 128);
    #pragma unroll 4
    for (int k4 = 0; k4 < 32; ++k4) {
        float4 wv = wr[k4];
        #pragma unroll
        for (int b = 0; b < 16; ++b) {
            float4 av = ((const float4*)ain)[b * 32 + k4];
            acc[b] += av.x*wv.x + av.y*wv.y + av.z*wv.z + av.w*wv.w;
        }
    }
    #pragma unroll
    for (int b = 0; b < 16; ++b)
        as_s[(((t >> 3) * 17 + b) << 3) | (t & 7)] = (__bf16)fmaxf(acc[b], 0.f);
    __syncthreads();

    const int w = t >> 6, lane = t & 63, l16 = lane & 15, quad = lane >> 4;
    if (w < 3) {
        f32x4 c = {0.f, 0.f, 0.f, 0.f};
        const __bf16* bp = wg_b + (size_t)(w * 16 + l16) * 512 + quad * 8;
        const __bf16* ap = &as_s[((quad * 17 + l16)) * 8];
        bf16x8 aC = *(const bf16x8*)ap;
        bf16x8 bC = *(const bf16x8*)bp;
        #pragma unroll
        for (int kt = 0; kt < 16; ++kt) {
            bf16x8 aN, bN;
            if (kt < 15) {
                aN = *(const bf16x8*)(ap + (kt + 1) * (4 * 17 * 8));
                bN = *(const bf16x8*)(bp + (kt + 1) * 32);
            }
            c = __builtin_amdgcn_mfma_f32_16x16x32_bf16(aC, bC, c, 0, 0, 0);
            if (kt < 15) { aC = aN; bC = bN; }
        }
        #pragma unroll
        for (int r = 0; r < 4; ++r)
            inter[(size_t)(bt0 + quad * 4 + r) * 48 + w * 16 + l16] = c[r];
    }
}

// ---------------------------------------------------------------- kernel 2
// STRUCTURAL REDESIGN (rounds 2-8 all flat at 155-170us, occupancy 21% =
// block lifetime ~80K cyc for ~10K of work -> serial phase chain + only 3
// blocks/CU). Changes:
//  - NO materialized vact[48][512] in LDS. content[48][48] computed PER-WAVE
//    from acc registers: relu+bias -> 16x128 transpose via 4KB private LDS
//    scratch (XOR-swizzled, reuses freed V-staging bufs, no block barrier)
//    -> 36 MFMA (K=128 slice) -> f32 atomicAdd into content_s[48][49].
//  - V staged via 2x12544B DOUBLE buffer (chunk=4kt), serial-at-end staging.
//  - LDS 51KB -> 34.3KB -> 4 blocks/CU; launch_bounds(256,2) pins VGPR cap
//    at 128 (decode: cap=256/arg2; round-8 core measured 124) -> 4 waves/SIMD.
//  - wv_b per-block reads 256KB -> 48KB; z via 3 waves, 12 tanh/thread.
// Watch: WRITE_SIZE jump >20MB = spill (cap too tight) -> revert to (256,1).
__global__ __launch_bounds__(256, 2) void main_fused(
    const float* __restrict__ video, const float* __restrict__ bvid,
    const __bf16* __restrict__ wvid_k, const __bf16* __restrict__ wv_b,
    const float* __restrict__ Wh, const float* __restrict__ inter_g,
    float* __restrict__ out) {

    __shared__ uint4 pool4[1568];        // 25088 B: V granule dbuf; scratch later
    __shared__ float content_s[48 * 49]; // 9408 B (+1 pad vs 48 for banks)
    __shared__ float inter_s[MDIM];
    __shared__ float z_s[MDIM];
    __shared__ float alpha_s[MDIM];

    char* pool = (char*)pool4;

    const int bt   = blockIdx.x;
    const int tid  = threadIdx.x;        // 0..255
    const int w    = tid >> 6;           // 0..3
    const int lane = tid & 63;
    const int l16  = lane & 15;
    const int quad = lane >> 4;

    const float* Vg = video + (size_t)bt * (48 * 512);
    const char*  bbase = (const char*)wvid_k;

    // ---- phase 0
    if (tid < MDIM) inter_s[tid] = inter_g[bt * MDIM + tid];
    #pragma unroll
    for (int i = tid; i < 48 * 49; i += 256) content_s[i] = 0.f;

    // staging map: kcl = tid&15 (kc within chunk), rows s = tid>>4 (+16,+32).
    // 16 lanes per s-row -> 512B coalesced global reads.
    const int kcl = tid & 15;
    const int s_b = tid >> 4;            // 0..15

    // ---- prologue: serial stage chunk 0 -> buf 0
    #pragma unroll
    for (int m = 0; m < 3; ++m) {
        const int s = s_b + m * 16;
        const float4* p = (const float4*)(Vg + s * 512 + kcl * 8);
        float4 x = p[0], y = p[1];
        bf16x8 g = {(__bf16)x.x, (__bf16)x.y, (__bf16)x.z, (__bf16)x.w,
                    (__bf16)y.x, (__bf16)y.y, (__bf16)y.z, (__bf16)y.w};
        *(bf16x8*)(pool + (kcl * 49 + s) * 16) = g;
    }

    // B byte addr for (kt,j): kt*32768 + quad*8192 + (w*128 + j*16 + l16)*16
    const int bIdx0 = quad * 8192 + (w * 128 + l16) * 16;

    bf16x8 bC[8];
    #pragma unroll
    for (int j = 0; j < 8; ++j)
        bC[j] = *(const bf16x8*)(bbase + bIdx0 + j * 256);

    f32x4 acc[3][8];
    #pragma unroll
    for (int mt = 0; mt < 3; ++mt)
        #pragma unroll
        for (int j = 0; j < 8; ++j) {
            f32x4 z = {0.f, 0.f, 0.f, 0.f};
            acc[mt][j] = z;
        }

    __syncthreads();

    // ---- phase 1+2: 4 chunks x 4 kt, double-buffered V, B 1-kt reg dbuf
    #pragma unroll
    for (int c = 0; c < 4; ++c) {
        const int rbuf = (c & 1) * 12544;
        #pragma unroll
        for (int k = 0; k < 4; ++k) {
            const int kt = c * 4 + k;
            bf16x8 a[3];
            #pragma unroll
            for (int mt = 0; mt < 3; ++mt)
                a[mt] = *(const bf16x8*)(pool + rbuf +
                            ((4 * k + quad) * 49 + mt * 16 + l16) * 16);
            bf16x8 bN[8];
            if (kt < 15) {
                #pragma unroll
                for (int j = 0; j < 8; ++j)
                    bN[j] = *(const bf16x8*)(bbase + bIdx0 + (kt + 1) * 32768 + j * 256);
            }
            __builtin_amdgcn_sched_barrier(0);   // loads stay above the MFMAs
            #pragma unroll
            for (int mt = 0; mt < 3; ++mt)
                #pragma unroll
                for (int j = 0; j < 8; ++j)
                    acc[mt][j] = __builtin_amdgcn_mfma_f32_16x16x32_bf16(
                                     a[mt], bC[j], acc[mt][j], 0, 0, 0);
            if (kt < 15) {
                #pragma unroll
                for (int j = 0; j < 8; ++j) bC[j] = bN[j];
            }
        }
        if (c < 3) {
            // serial stage of chunk c+1 into the other buffer
            const int wbuf = ((c + 1) & 1) * 12544;
            float4 px[3], py[3];
            #pragma unroll
            for (int m = 0; m < 3; ++m) {
                const int s = s_b + m * 16;
                const float4* p = (const float4*)(Vg + s * 512 + ((c + 1) * 16 + kcl) * 8);
                px[m] = p[0]; py[m] = p[1];
            }
            #pragma unroll
            for (int m = 0; m < 3; ++m) {
                const int s = s_b + m * 16;
                bf16x8 g = {(__bf16)px[m].x, (__bf16)px[m].y, (__bf16)px[m].z, (__bf16)px[m].w,
                            (__bf16)py[m].x, (__bf16)py[m].y, (__bf16)py[m].z, (__bf16)py[m].w};
                *(bf16x8*)(pool + wbuf + (kcl * 49 + s) * 16) = g;
            }
        }
        __syncthreads();   // next chunk visible; final one = all granule reads done
    }

    // ---- phase 3 (per-wave, no block barrier): content += vact_w @ Wv^T
    // Wave w owns h in [128w, 128w+128). Transpose acc (col=h,row=s) into
    // A-frags (row=s, k=h) via 4KB private scratch in the freed V buffers.
    {
        char* scr = pool + w * 4096;
        float bias_j[8];
        #pragma unroll
        for (int j = 0; j < 8; ++j) bias_j[j] = bvid[w * 128 + j * 16 + l16];

        #pragma unroll
        for (int mt = 0; mt < 3; ++mt) {
            // write 16(s') x 128(h') bf16 tile, XOR-swizzled by row
            #pragma unroll
            for (int j = 0; j < 8; ++j) {
                #pragma unroll
                for (int r = 0; r < 4; ++r) {
                    const int sp = quad * 4 + r;
                    const int h2 = (j * 16 + l16) * 2;
                    *(__bf16*)(scr + sp * 256 + (h2 ^ ((sp & 7) << 5))) =
                        (__bf16)fmaxf(acc[mt][j][r] + bias_j[j], 0.f);
                }
            }
            // read A-frags (row=l16, k-slice ks) and MFMA vs Wv
            f32x4 cc[3];
            #pragma unroll
            for (int nt = 0; nt < 3; ++nt) { f32x4 z = {0.f,0.f,0.f,0.f}; cc[nt] = z; }
            #pragma unroll
            for (int ks = 0; ks < 4; ++ks) {
                bf16x8 pa = *(const bf16x8*)(scr + l16 * 256 +
                                ((ks * 64 + quad * 16) ^ ((l16 & 7) << 5)));
                #pragma unroll
                for (int nt = 0; nt < 3; ++nt) {
                    bf16x8 pb = *(const bf16x8*)(wv_b + (size_t)(nt * 16 + l16) * 512 +
                                                 w * 128 + ks * 32 + quad * 8);
                    cc[nt] = __builtin_amdgcn_mfma_f32_16x16x32_bf16(pa, pb, cc[nt], 0, 0, 0);
                }
            }
            #pragma unroll
            for (int nt = 0; nt < 3; ++nt)
                #pragma unroll
                for (int r = 0; r < 4; ++r)
                    atomicAdd(&content_s[(mt * 16 + quad * 4 + r) * 49 + nt * 16 + l16],
                              cc[nt][r]);
        }
    }
    __syncthreads();

    // ---- phase 3b: z[s] = sum_m tanh(content[s][m] + inter[s]) * Wh[m]
    // waves 0-2: lane -> (s = 16w + lane>>2, q = lane&3 covers 12 m each)
    if (w < 3) {
        const int s = 16 * w + (lane >> 2);
        const int q = lane & 3;
        const float ins = inter_s[s];
        float zp = 0.f;
        #pragma unroll
        for (int mm = 0; mm < 12; ++mm) {
            const int m = q * 12 + mm;
            zp += tanhf(content_s[s * 49 + m] + ins) * Wh[m];
        }
        zp += __shfl_xor(zp, 1);
        zp += __shfl_xor(zp, 2);
        if (q == 0) z_s[s] = zp;
    }
    __syncthreads();

    // ---- phase 4: softmax over z[48] (wave 0)
    if (w == 0) {
        float x = (lane < MDIM) ? z_s[lane] : -INFINITY;
        float mx = x;
        #pragma unroll
        for (int off = 32; off >= 1; off >>= 1) mx = fmaxf(mx, __shfl_xor(mx, off));
        float e = (lane < MDIM) ? expf(x - mx) : 0.f;
        float sm = e;
        #pragma unroll
        for (int off = 32; off >= 1; off >>= 1) sm += __shfl_xor(sm, off);
        if (lane < MDIM) alpha_s[lane] = e / sm;
    }
    __syncthreads();

    // ---- phase 5: c[h] = sum_s alpha[s] * V[s][h]; 2 h per thread
    float a5 = 0.f, b5 = 0.f;
    #pragma unroll
    for (int s = 0; s < MDIM; ++s) {
        const float al = alpha_s[s];
        a5 += al * Vg[s * 512 + tid];
        b5 += al * Vg[s * 512 + 256 + tid];
    }
    out[(size_t)bt * 512 + tid]       = a5;
    out[(size_t)bt * 512 + 256 + tid] = b5;
}

// ---------------------------------------------------------------- launch
extern "C" void kernel_launch(void* const* d_in, const int* in_sizes, int n_in,
                              void* d_out, int out_size, void* d_ws, size_t ws_size,
                              hipStream_t stream) {
    const float* audio   = (const float*)d_in[0];
    const float* video   = (const float*)d_in[1];
    const float* W_audio = (const float*)d_in[2];
    const float* b_audio = (const float*)d_in[3];
    const float* W_video = (const float*)d_in[4];
    const float* b_video = (const float*)d_in[5];
    const float* W_v     = (const float*)d_in[6];
    const float* W_g     = (const float*)d_in[7];
    const float* W_h     = (const float*)d_in[8];
    float* out = (float*)d_out;

    char* ws = (char*)d_ws;
    __bf16* wvid_k = (__bf16*)(ws + WS_WVID);
    __bf16* wv_b   = (__bf16*)(ws + WS_WV);
    __bf16* wg_b   = (__bf16*)(ws + WS_WG);
    float*  inter  = (float*)(ws + WS_INTER);

    convert_weights<<<304, 256, 0, stream>>>(W_video, W_v, W_g, wvid_k, wv_b, wg_b);
    audio_batch<<<BT / 16, 512, 0, stream>>>(audio, W_audio, b_audio, wg_b, inter);
    main_fused<<<BT, 256, 0, stream>>>(video, b_video, wvid_k, wv_b, W_h, inter, out);
}